// Round 2
// baseline (389.051 us; speedup 1.0000x reference)
//
#include <hip/hip_runtime.h>
#include <cstdint>
#include <cstddef>

// LLAConv2d: per-sample 1x1 conv == 32 independent GEMMs
//   out[b,o,p] = sum_i K[b,o,i] * x[b,i,p],  K[b] = sum_e alpha[b,e]*ke[e]
// B=32, Cin=Cout=64, P=160*160=25600, fp32.
// Floors: HBM ~67us (420MB @6.3TB/s), fp32 VALU ~43us (no fp32 MFMA on CDNA4).
// R2/R3 (~110-139us) were LDS-pipe-bound: 3 ds_read_b128 per 32 FMAs
// (768 LDS instrs / 768KB per block-tile) ~= 80-96us of LDS pipe time.
// R4: wave owns 16 output channels -> k is wave-uniform -> k via SCALAR loads
// from global (SMEM pipe, kt L2-resident), zero LDS for k. x read as 1
// ds_read_b64 per K-step (512B/wave contiguous). LDS traffic 6x down.
// Grid-stride 512 blocks (2/CU, one residency round, no ragged tail).

#define PIX 25600
#define CIN 64
#define COUT 64
#define BATCH 32
#define NEXP 8
#define TILE_PX 128
#define TILES_PER_B (PIX / TILE_PX)     // 200
#define TOT_TILES (BATCH * TILES_PER_B) // 6400
#define GRID 512                        // 2 blocks/CU, all co-resident

__device__ __forceinline__ void load_lds16(const float* g, float* l) {
  // async global->LDS, 16B/lane; global addr per-lane, LDS dst uniform+lane*16
  __builtin_amdgcn_global_load_lds(
      (__attribute__((address_space(1))) void*)(g),
      (__attribute__((address_space(3))) void*)(l), 16, 0, 0);
}

// ---------------- Kernel A: mix kernels, store TRANSPOSED kt[b][i][o] -------
__global__ __launch_bounds__(256) void mix_kernel(
    const float* __restrict__ alpha, const float* __restrict__ ke,
    float* __restrict__ kt) {
  const int b = blockIdx.x >> 3;
  const int seg = blockIdx.x & 7;
  __shared__ float a[NEXP];
  if (threadIdx.x < NEXP) a[threadIdx.x] = alpha[b * NEXP + threadIdx.x];
  __syncthreads();
#pragma unroll
  for (int t = 0; t < 2; t++) {
    const int idx = seg * 512 + t * 256 + threadIdx.x; // idx = o*64 + i
    float s = 0.f;
#pragma unroll
    for (int e = 0; e < NEXP; e++) s += a[e] * ke[e * 4096 + idx];
    const int o = idx >> 6, i = idx & 63;
    kt[b * 4096 + i * 64 + o] = s; // transposed: [i][o]
  }
}

// ---------------- Kernel B: grid-stride pipelined 1x1-conv GEMM -------------
// 512 blocks x 256 threads; block processes tiles bid, bid+512, ... (12-13).
// Wave w computes out-channels [16w,16w+16) x all 128 px (lane = 2 px).
// k[ii][16w..16w+16) is wave-uniform -> scalar loads (readfirstlane'd wave id).
// LDS: xs[2][64][128] = 64KB dbuf -> 2 blocks/CU (8 waves/CU).
// Per-wave vmcnt ledger (global_load_lds + stores share vmcnt, FIFO):
//   stage = 8 instrs/tile, stores = 16 instrs/tile.
//   first iter:  [stage_cur 8][stage_next 8]           -> wait vmcnt(8)
//   mid iter:    [stage_cur 8][stores 16][stage_next 8] -> wait vmcnt(24)
//   last iter:   [stage_cur 8][stores 16]               -> wait vmcnt(16)
// Raw s_barrier (no drain): prefetch loads + stores stay in flight.
__global__ __launch_bounds__(256, 2) void conv_kernel(
    const float* __restrict__ x, const float* __restrict__ kt,
    float* __restrict__ out) {
  __shared__ float xs[2][CIN * TILE_PX];

  const int bid = blockIdx.x;
  const int tid = threadIdx.x;
  const int wave = tid >> 6;
  const int lane = tid & 63;
  // force wave id into an SGPR so k addresses are provably wave-uniform
  const int wu = __builtin_amdgcn_readfirstlane(wave);

  // Prologue: stage tile 'bid' into xs[0]. Wave w stages rows 16w..16w+15,
  // 2 rows/instr (lanes 0-31 -> row r, 32-63 -> r+1; 512B contiguous/row).
  {
    const int b0 = bid / TILES_PER_B;
    const int tl0 = bid - b0 * TILES_PER_B;
    const float* gs = x + (size_t)b0 * CIN * PIX + (size_t)tl0 * TILE_PX;
#pragma unroll
    for (int j = 0; j < 8; j++) {
      const int r = wave * 16 + j * 2;
      load_lds16(gs + (size_t)(r + (lane >> 5)) * PIX + (lane & 31) * 4,
                 &xs[0][r * TILE_PX]);
    }
  }

  int cur = 0;
  for (int t = bid; t < TOT_TILES; t += GRID) {
    const int b = t / TILES_PER_B;
    const int tl = t - b * TILES_PER_B;
    const int tn = t + GRID;
    const bool has_next = (tn < TOT_TILES);

    if (t != bid) {
      // all waves done reading xs[cur^1] (prev tile) before overwrite below
      __builtin_amdgcn_s_barrier();
      asm volatile("" ::: "memory");
    }

    if (has_next) {
      const int bn = tn / TILES_PER_B;
      const int tln = tn - bn * TILES_PER_B;
      const float* gs = x + (size_t)bn * CIN * PIX + (size_t)tln * TILE_PX;
      float* dst = xs[cur ^ 1];
#pragma unroll
      for (int j = 0; j < 8; j++) {
        const int r = wave * 16 + j * 2;
        load_lds16(gs + (size_t)(r + (lane >> 5)) * PIX + (lane & 31) * 4,
                   dst + r * TILE_PX);
      }
    }

    // counted wait: current tile's stage loads (oldest) complete; next tile's
    // loads and previous tile's stores stay in flight across the barrier
    if (t == bid) {
      if (has_next) {
        asm volatile("s_waitcnt vmcnt(8)" ::: "memory");
      } else {
        asm volatile("s_waitcnt vmcnt(0)" ::: "memory");
      }
    } else {
      if (has_next) {
        asm volatile("s_waitcnt vmcnt(24)" ::: "memory");
      } else {
        asm volatile("s_waitcnt vmcnt(16)" ::: "memory");
      }
    }
    __builtin_amdgcn_s_barrier(); // raw: no vmcnt drain
    asm volatile("" ::: "memory");

    float acc[16][2];
#pragma unroll
    for (int c = 0; c < 16; c++) {
      acc[c][0] = 0.f;
      acc[c][1] = 0.f;
    }

    // k: wave-uniform scalar loads (SMEM pipe, no LDS, no vmcnt).
    // x: lane reads its 2 px (8B) of the 512B row -> contiguous, conflict-free.
    const float* kb = kt + b * 4096 + wu * 16;
    const float* xp = &xs[cur][lane * 2];
#pragma unroll 4
    for (int ii = 0; ii < CIN; ii++) {
      const float2 xv = *(const float2*)(xp + ii * TILE_PX);
      const float* kr = kb + ii * 64;
#pragma unroll
      for (int c = 0; c < 16; c++) {
        const float kv = kr[c];
        acc[c][0] = fmaf(kv, xv.x, acc[c][0]);
        acc[c][1] = fmaf(kv, xv.y, acc[c][1]);
      }
    }

    // Epilogue: 16 x float2 stores; 64 lanes cover 512B contiguous per chan.
    float* ob = out + ((size_t)(b * COUT + wu * 16)) * PIX +
                (size_t)tl * TILE_PX + lane * 2;
#pragma unroll
    for (int c = 0; c < 16; c++) {
      *(float2*)(ob + (size_t)c * PIX) = make_float2(acc[c][0], acc[c][1]);
    }

    cur ^= 1;
  }
}

extern "C" void kernel_launch(void* const* d_in, const int* in_sizes, int n_in,
                              void* d_out, int out_size, void* d_ws,
                              size_t ws_size, hipStream_t stream) {
  const float* x = (const float*)d_in[0];     // [32,64,160,160]
  const float* alpha = (const float*)d_in[1]; // [32,8]
  const float* ke = (const float*)d_in[2];    // [8,64,64,1,1]
  float* out = (float*)d_out;                 // [32,64,160,160]
  float* kt = (float*)d_ws;                   // 32*4096 floats = 512KB scratch

  mix_kernel<<<BATCH * 8, 256, 0, stream>>>(alpha, ke, kt);
  conv_kernel<<<GRID, 256, 0, stream>>>(x, kt, out);
}